// Round 4
// baseline (48.118 us; speedup 1.0000x reference)
//
#include <hip/hip_runtime.h>

#define NUM_BINS 256
#define PLANES 48                    // B*C = 16*3
#define PLANE_ELEMS (512 * 512)      // H*W
#define BPP 16                       // blocks per plane
#define THREADS 128
#define ROWSTRIDE 264                // bytes per thread-row: 256 bins + dummy@256 + pad (word-aligned)
#define F4_PER_BLOCK (PLANE_ELEMS / 4 / BPP)   // 4096 float4 per block
#define CHUNK_F4 8                   // float4 per load batch per thread
#define NCHUNK (F4_PER_BLOCK / (CHUNK_F4 * THREADS))   // 4

__global__ __launch_bounds__(THREADS) void hist_kernel(const float* __restrict__ pred,
                                                       const float* __restrict__ target,
                                                       unsigned* __restrict__ hist,
                                                       unsigned* __restrict__ totals) {
    __shared__ unsigned char lh[THREADS * ROWSTRIDE];
    const int t = threadIdx.x;

    unsigned* lw = reinterpret_cast<unsigned*>(lh);
    for (int i = t; i < THREADS * ROWSTRIDE / 4; i += THREADS) lw[i] = 0u;
    __syncthreads();

    const int gid   = blockIdx.x;
    const int which = gid / (PLANES * BPP);
    const int rem   = gid - which * (PLANES * BPP);
    const int plane = rem / BPP;
    const int cblk  = rem - plane * BPP;

    const float* src = which ? target : pred;
    const float4* p = reinterpret_cast<const float4*>(src + (size_t)plane * PLANE_ELEMS)
                      + (size_t)cblk * F4_PER_BLOCK;

    unsigned char* row = lh + (size_t)t * ROWSTRIDE;   // thread-private u8 histogram

    for (int c = 0; c < NCHUNK; ++c) {
        // 8 independent float4 loads in flight
        float4 v[CHUNK_F4];
#pragma unroll
        for (int j = 0; j < CHUNK_F4; ++j)
            v[j] = p[c * (CHUNK_F4 * THREADS) + j * THREADS + t];

        // process 32 elements in 4 batches of 8 (batched reads + in-register dup fix)
#pragma unroll
        for (int bb = 0; bb < CHUNK_F4 / 2; ++bb) {
            float e[8] = {v[2*bb].x,   v[2*bb].y,   v[2*bb].z,   v[2*bb].w,
                          v[2*bb+1].x, v[2*bb+1].y, v[2*bb+1].z, v[2*bb+1].w};
            int b[8];
#pragma unroll
            for (int i = 0; i < 8; ++i) {
                float x = e[i];
                int bi = (int)(x * 256.0f);           // == floor for x >= 0
                bi = bi > 255 ? 255 : bi;             // x == 1.0 -> last bin
                b[i] = (x >= 0.0f && x <= 1.0f) ? bi : 256;  // out-of-range -> dummy slot
            }
            unsigned char vv[8];
#pragma unroll
            for (int i = 0; i < 8; ++i) vv[i] = row[b[i]];   // batched ds_read_u8
#pragma unroll
            for (int i = 0; i < 8; ++i) {
                int inc = 1;
#pragma unroll
                for (int j = 0; j < i; ++j) inc += (b[i] == b[j]) ? 1 : 0;
                row[b[i]] = (unsigned char)(vv[i] + inc);    // ordered writes: last wins
            }
        }
    }
    __syncthreads();

    // merge: sum word-columns over the 128 thread-rows (bins 0..255 = words 0..63)
    if (t < 64) {
        unsigned even = 0, odd = 0;   // each packs 2 x u16 accumulators
        for (int r = 0; r < THREADS; ++r) {
            unsigned w = *reinterpret_cast<const unsigned*>(lh + (size_t)r * ROWSTRIDE + t * 4);
            even += w & 0x00FF00FFu;
            odd  += (w >> 8) & 0x00FF00FFu;
        }
        unsigned c0 = even & 0xFFFFu, c2 = even >> 16;
        unsigned c1 = odd  & 0xFFFFu, c3 = odd  >> 16;
        unsigned* gh = hist + (size_t)(which * PLANES + plane) * NUM_BINS;
        if (c0) atomicAdd(&gh[4*t + 0], c0);
        if (c1) atomicAdd(&gh[4*t + 1], c1);
        if (c2) atomicAdd(&gh[4*t + 2], c2);
        if (c3) atomicAdd(&gh[4*t + 3], c3);

        unsigned bt = c0 + c1 + c2 + c3;               // block's in-range count
        for (int off = 32; off; off >>= 1) bt += __shfl_down(bt, off, 64);
        if (t == 0) atomicAdd(&totals[which * PLANES + plane], bt);
    }
}

__global__ __launch_bounds__(1024) void loss_kernel(const unsigned* __restrict__ hist,
                                                    const unsigned* __restrict__ totals,
                                                    float* __restrict__ out) {
    __shared__ double inv[2 * PLANES];
    __shared__ double sd[16];
    const int t = threadIdx.x;
    if (t < 2 * PLANES) inv[t] = 1.0 / ((double)totals[t] + 1e-8);
    __syncthreads();

    const uint4* h4 = reinterpret_cast<const uint4*>(hist);
    double acc = 0.0;
    for (int i = t; i < (PLANES * NUM_BINS) / 4; i += 1024) {
        uint4 hp = h4[i];
        uint4 ht = h4[i + (PLANES * NUM_BINS) / 4];
        const double ip = inv[i >> 6];
        const double it = inv[PLANES + (i >> 6)];
        double d0 = (double)hp.x * ip - (double)ht.x * it;
        double d1 = (double)hp.y * ip - (double)ht.y * it;
        double d2 = (double)hp.z * ip - (double)ht.z * it;
        double d3 = (double)hp.w * ip - (double)ht.w * it;
        acc += d0 * d0 + d1 * d1 + d2 * d2 + d3 * d3;
    }
    for (int off = 32; off; off >>= 1) acc += __shfl_down(acc, off, 64);
    if ((t & 63) == 0) sd[t >> 6] = acc;
    __syncthreads();
    if (t == 0) {
        double s = 0.0;
        for (int w = 0; w < 16; ++w) s += sd[w];
        out[0] = (float)(s / (double)(PLANES * NUM_BINS));
    }
}

extern "C" void kernel_launch(void* const* d_in, const int* in_sizes, int n_in,
                              void* d_out, int out_size, void* d_ws, size_t ws_size,
                              hipStream_t stream) {
    const float* pred   = (const float*)d_in[0];
    const float* target = (const float*)d_in[1];
    float* out = (float*)d_out;
    unsigned* hist   = (unsigned*)d_ws;                          // [2][48][256] u32
    unsigned* totals = hist + (size_t)2 * PLANES * NUM_BINS;     // [96] u32

    hipMemsetAsync(d_ws, 0, ((size_t)2 * PLANES * NUM_BINS + 2 * PLANES) * sizeof(unsigned), stream);
    hist_kernel<<<2 * PLANES * BPP, THREADS, 0, stream>>>(pred, target, hist, totals);
    loss_kernel<<<1, 1024, 0, stream>>>(hist, totals, out);
}